// Round 11
// baseline (4625.904 us; speedup 1.0000x reference)
//
#include <hip/hip_runtime.h>
#include <stdint.h>
#include <stddef.h>

typedef __attribute__((ext_vector_type(8))) short short8;
typedef __attribute__((ext_vector_type(4))) float f32x4;
typedef __attribute__((ext_vector_type(2))) float f32x2;

#define MFMA16(A, B, C) __builtin_amdgcn_mfma_f32_16x16x32_bf16((A), (B), (C), 0, 0, 0)

// ---------- workspace layout (bytes) ----------
static const size_t OFF_XB   = 0;                    // x bf16      [64*512, 1024]  67108864
static const size_t OFF_WIH  = 67108864;             // w_ih bf16   [4096, 1024]     8388608
static const size_t OFF_WHH  = 75497472;             // w_hh bf16   [4096, 1024]     8388608
static const size_t OFF_BIAS = 83886080;             // b_ih+b_hh   [4096] f32         16384
static const size_t OFF_H0   = 83902464;             // h buf 0 bf16 [64,1024]        131072
static const size_t OFF_H1   = 84033536;             // h buf 1 bf16                  131072
static const size_t OFF_FLG  = 84164608;             // u32[512]: ctrA[g]=[g*32], ctrB[g]=[256+g*32]
static const size_t OFF_XW   = 84426752;             // xW [512*64, 4096] f32 or bf16
static const size_t XW_F32_BYTES = 536870912;

__device__ __forceinline__ unsigned short f2bf(float f) {
    union { float f; uint32_t u; } v; v.f = f;
    uint32_t u = v.u;
    u += 0x7FFFu + ((u >> 16) & 1u);   // round-to-nearest-even
    return (unsigned short)(u >> 16);
}
__device__ __forceinline__ float bf2f(unsigned short b) {
    union { uint32_t u; float f; } v; v.u = ((uint32_t)b) << 16;
    return v.f;
}

__device__ __forceinline__ float fast_sigmoid(float x) {
    return 1.f / (1.f + __expf(-x));
}
__device__ __forceinline__ float fast_tanh(float x) {
    return 1.f - 2.f / (__expf(2.f * x) + 1.f);
}

// ---------- cast fp32 -> bf16, 4 elems/thread ----------
__global__ __launch_bounds__(256) void cast4_kernel(const float* __restrict__ s,
                                                    unsigned short* __restrict__ d, int n4) {
    int i = blockIdx.x * 256 + threadIdx.x;
    if (i >= n4) return;
    float4 f = ((const float4*)s)[i];
    ushort4 o;
    o.x = f2bf(f.x); o.y = f2bf(f.y); o.z = f2bf(f.z); o.w = f2bf(f.w);
    ((ushort4*)d)[i] = o;
}

// ---------- bias fold + h0 init + counter zero ----------
__global__ __launch_bounds__(256) void init_misc(const float* __restrict__ b_ih,
                                                 const float* __restrict__ b_hh,
                                                 float* __restrict__ bias,
                                                 const float* __restrict__ h0,
                                                 unsigned short* __restrict__ h_ini,
                                                 unsigned int* __restrict__ flags) {
    int i = blockIdx.x * 256 + threadIdx.x;
    if (i < 512) flags[i] = 0u;
    if (i < 4096) bias[i] = b_ih[i] + b_hh[i];
    if (i < 65536) h_ini[i] = f2bf(h0[i]);
}

// ---------- xW GEMM: C[t*64+b][g] = sum_k x[b*512+t][k] * w_ih[g][k] + bias[g] ----------
template <bool XWF32>
__global__ __launch_bounds__(256) void xw_gemm(const unsigned short* __restrict__ xb,
                                               const unsigned short* __restrict__ wb,
                                               const float* __restrict__ bias,
                                               void* __restrict__ xw) {
    __shared__ __align__(16) unsigned short As[128 * 32];
    __shared__ __align__(16) unsigned short Bs[128 * 32];
    const int bm = blockIdx.x, bn = blockIdx.y;
    const int tid = threadIdx.x;
    const int wave = tid >> 6, lane = tid & 63;
    const int wm = (wave >> 1) * 64, wn = (wave & 1) * 64;
    const int lr = lane & 15, lk = (lane >> 4) * 8;

    const int c0 = tid, c1 = tid + 256;
    const int r0 = c0 >> 2, k0c = (c0 & 3) * 8;
    const int r1 = c1 >> 2, k1c = (c1 & 3) * 8;
    const int mA0 = bm * 128 + r0, mA1 = bm * 128 + r1;
    const unsigned short* pa0 = xb + (size_t)(((mA0 & 63) << 9) + (mA0 >> 6)) * 1024 + k0c;
    const unsigned short* pa1 = xb + (size_t)(((mA1 & 63) << 9) + (mA1 >> 6)) * 1024 + k1c;
    const unsigned short* pb0 = wb + (size_t)(bn * 128 + r0) * 1024 + k0c;
    const unsigned short* pb1 = wb + (size_t)(bn * 128 + r1) * 1024 + k1c;
    unsigned short* sa0 = As + r0 * 32 + k0c;
    unsigned short* sa1 = As + r1 * 32 + k1c;
    unsigned short* sb0 = Bs + r0 * 32 + k0c;
    unsigned short* sb1 = Bs + r1 * 32 + k1c;

    f32x4 acc[4][4] = {};

    for (int kk = 0; kk < 32; ++kk) {
        const int ko = kk * 32;
        uint4 av0 = *(const uint4*)(pa0 + ko);
        uint4 av1 = *(const uint4*)(pa1 + ko);
        uint4 bv0 = *(const uint4*)(pb0 + ko);
        uint4 bv1 = *(const uint4*)(pb1 + ko);
        __syncthreads();
        *(uint4*)sa0 = av0;
        *(uint4*)sa1 = av1;
        *(uint4*)sb0 = bv0;
        *(uint4*)sb1 = bv1;
        __syncthreads();
        short8 af[4], bfr[4];
#pragma unroll
        for (int mi = 0; mi < 4; ++mi)
            af[mi] = *(const short8*)(As + (wm + mi * 16 + lr) * 32 + lk);
#pragma unroll
        for (int ni = 0; ni < 4; ++ni)
            bfr[ni] = *(const short8*)(Bs + (wn + ni * 16 + lr) * 32 + lk);
#pragma unroll
        for (int mi = 0; mi < 4; ++mi)
#pragma unroll
            for (int ni = 0; ni < 4; ++ni)
                acc[mi][ni] = MFMA16(af[mi], bfr[ni], acc[mi][ni]);
    }

    const int rbase = (lane >> 4) * 4;
#pragma unroll
    for (int ni = 0; ni < 4; ++ni) {
        const int gc = bn * 128 + wn + ni * 16 + lr;
        const float bv = bias[gc];
#pragma unroll
        for (int mi = 0; mi < 4; ++mi) {
            const int gr = bm * 128 + wm + mi * 16 + rbase;
#pragma unroll
            for (int r = 0; r < 4; ++r) {
                float v = acc[mi][ni][r] + bv;
                if (XWF32) ((float*)xw)[(size_t)(gr + r) * 4096 + gc] = v;
                else ((unsigned short*)xw)[(size_t)(gr + r) * 4096 + gc] = f2bf(v);
            }
        }
    }
}

// ---------- persistent recurrence: batch-interleaved dual pipelines ----------
// 64 blocks x 512 thr. Batches split: half A = 0..31, half B = 32..63, independent
// recurrences with separate counters. Per iteration: pollA -> h_A loads -> MFMA_A ->
// partials A -> sync -> pollB + issue h_B loads (latency hides under reduce A) ->
// reduce A + gates A -> h_A store -> drain -> sync -> sigA -> MFMA_B -> partials B ->
// sync -> reduce B + gates B -> h_B store -> drain -> sync -> sigB -> out/xW tail.
// Each half's signal->poll propagation is covered by the OTHER half's compute.
template <bool XWF32>
__global__ __launch_bounds__(512, 2) void lstm_persistent(
        unsigned short* hb0, unsigned short* hb1,
        const void* __restrict__ xw,
        const unsigned short* __restrict__ whh,
        const float* __restrict__ fb,
        const float* __restrict__ c0,
        float* __restrict__ out,
        float* __restrict__ hcout,
        unsigned int* ctr) {
    __shared__ __align__(16) float part[8 * 32 * 64];   // [kq][batch_half][out] 65536 B

    const int tid = threadIdx.x;
    const int wave = tid >> 6, lane = tid & 63;
    const int bk = blockIdx.x, ch0 = bk * 16;
    const int kq = wave;                 // K-slice owner
    const int lr = lane & 15, g = lane >> 4;

    // ---- W_hh fragments -> registers, once ----
    short8 Wf[4][4];
#pragma unroll
    for (int ni = 0; ni < 4; ++ni)
#pragma unroll
        for (int ks = 0; ks < 4; ++ks) {
            const unsigned short* p = whh + (size_t)(ni * 1024 + ch0 + lr) * 1024
                                          + kq * 128 + ks * 32 + g * 8;
            asm volatile("global_load_dwordx4 %0, %1, off"
                         : "=&v"(Wf[ni][ks]) : "v"(p));
        }
    asm volatile("s_waitcnt vmcnt(0)" ::: "memory");
    __builtin_amdgcn_sched_barrier(0);

    // ---- per-thread epilogue map: thread owns (batch bb within half, channel jj) ----
    const int jj = tid & 15;
    const int bb = tid >> 4;             // 0..31
    const int ch = ch0 + jj;
    const float fbv = fb[ch];
    float cA = c0[bb * 1024 + ch];
    float cB = c0[(32 + bb) * 1024 + ch];

    // ---- loop-invariant LDS indices (swizzled; write rows = batch, slot = out) ----
    int wsl[4];
#pragma unroll
    for (int oi = 0; oi < 4; ++oi)
        wsl[oi] = kq * 2048 + lr * 64 + ((((oi * 4 + g) ^ (lr & 7))) << 2);
    int rsl[4];
#pragma unroll
    for (int g4 = 0; g4 < 4; ++g4)
        rsl[g4] = bb * 64 + ((((g4 * 4 + (jj >> 2)) ^ (bb & 7))) << 2) + (jj & 3);

    // ---- pointers / sync addresses ----
    const float* xw32 = (const float*)xw;
    const unsigned short* xw16 = (const unsigned short*)xw;
    const size_t xbA = (size_t)bb * 4096 + ch;
    const size_t xbB = (size_t)(32 + bb) * 4096 + ch;
    float* orA = out + (size_t)bb * 524288 + ch;
    float* orB = out + (size_t)(32 + bb) * 524288 + ch;
    unsigned int* sigA = &ctr[(bk >> 3) * 32];
    unsigned int* sigB = &ctr[256 + (bk >> 3) * 32];
    unsigned int* polA = &ctr[kq * 32];
    unsigned int* polB = &ctr[256 + kq * 32];

    // ---- xW prefetch t=0 ----
    float xwA[4], xwB[4];
#pragma unroll
    for (int g4 = 0; g4 < 4; ++g4) {
        if constexpr (XWF32) {
            xwA[g4] = xw32[xbA + g4 * 1024];
            xwB[g4] = xw32[xbB + g4 * 1024];
        } else {
            xwA[g4] = bf2f(xw16[xbA + g4 * 1024]);
            xwB[g4] = bf2f(xw16[xbB + g4 * 1024]);
        }
    }

    float hA = 0.f, hB = 0.f;

    for (int t = 0; t < 512; ++t) {
        const unsigned short* hp = (t & 1) ? hb1 : hb0;
        unsigned short* hn       = (t & 1) ? hb0 : hb1;
        const unsigned short* hbase = hp + (size_t)lr * 1024 + kq * 128 + g * 8;

        // ===================== half A =====================
        if (t > 0) {
            const unsigned tgt = (unsigned)t * 8u;
            while (__hip_atomic_load(polA, __ATOMIC_RELAXED,
                                     __HIP_MEMORY_SCOPE_AGENT) < tgt) {}
        }
        __builtin_amdgcn_sched_barrier(0);

        short8 afA[2][4];
#pragma unroll
        for (int bi = 0; bi < 2; ++bi) {
            const unsigned short* p = hbase + (size_t)bi * 16 * 1024;
            asm volatile(
                "global_load_dwordx4 %0, %4, off sc1\n\t"
                "global_load_dwordx4 %1, %4, off offset:64 sc1\n\t"
                "global_load_dwordx4 %2, %4, off offset:128 sc1\n\t"
                "global_load_dwordx4 %3, %4, off offset:192 sc1"
                : "=&v"(afA[bi][0]), "=&v"(afA[bi][1]),
                  "=&v"(afA[bi][2]), "=&v"(afA[bi][3])
                : "v"(p));
        }
        asm volatile("s_waitcnt vmcnt(0)" ::: "memory");
        __builtin_amdgcn_sched_barrier(0);

        {
            f32x4 acc[4][2] = {};
#pragma unroll
            for (int ks = 0; ks < 4; ++ks)
#pragma unroll
                for (int oi = 0; oi < 4; ++oi)
#pragma unroll
                    for (int bi = 0; bi < 2; ++bi)
                        acc[oi][bi] = MFMA16(Wf[oi][ks], afA[bi][ks], acc[oi][bi]);
#pragma unroll
            for (int oi = 0; oi < 4; ++oi)
#pragma unroll
                for (int bi = 0; bi < 2; ++bi)
                    *(f32x4*)&part[wsl[oi] + bi * 1024] = acc[oi][bi];
        }
        __syncthreads();   // sync1: partials A visible

        // ---- poll B + issue h_B loads (latency hides under reduce A) ----
        if (t > 0) {
            const unsigned tgt = (unsigned)t * 8u;
            while (__hip_atomic_load(polB, __ATOMIC_RELAXED,
                                     __HIP_MEMORY_SCOPE_AGENT) < tgt) {}
        }
        __builtin_amdgcn_sched_barrier(0);
        short8 afB[2][4];
#pragma unroll
        for (int bi = 0; bi < 2; ++bi) {
            const unsigned short* p = hbase + (size_t)(32 + bi * 16) * 1024;
            asm volatile(
                "global_load_dwordx4 %0, %4, off sc1\n\t"
                "global_load_dwordx4 %1, %4, off offset:64 sc1\n\t"
                "global_load_dwordx4 %2, %4, off offset:128 sc1\n\t"
                "global_load_dwordx4 %3, %4, off offset:192 sc1"
                : "=&v"(afB[bi][0]), "=&v"(afB[bi][1]),
                  "=&v"(afB[bi][2]), "=&v"(afB[bi][3])
                : "v"(p));
        }
        __builtin_amdgcn_sched_barrier(0);

        // ---- reduce A + gates A ----
        {
            float l[4];
#pragma unroll
            for (int g4 = 0; g4 < 4; ++g4) {
                float s = xwA[g4];
#pragma unroll
                for (int k8 = 0; k8 < 8; ++k8)
                    s += part[k8 * 2048 + rsl[g4]];
                l[g4] = s;
            }
            const float rg = fast_sigmoid(l[0] - fbv);
            const float fg = fast_sigmoid(l[1] + fbv);
            const float ug = fast_tanh(l[2]);
            const float og = fast_sigmoid(l[3]);
            const float of = 1.f - fg;
            const float gg = rg * (1.f - of * of) + (1.f - rg) * (fg * fg);
            cA = gg * cA + (1.f - gg) * ug;
            hA = og * fast_tanh(cA);
            const unsigned hw = (unsigned)f2bf(hA);
            asm volatile("global_store_short %0, %1, off sc1"
                         :: "v"(hn + bb * 1024 + ch), "v"(hw) : "memory");
        }
        asm volatile("s_waitcnt vmcnt(0)" ::: "memory");   // h_A at L3; afB complete
        __syncthreads();   // sync2
        if (tid == 0)
            __hip_atomic_fetch_add(sigA, 1u, __ATOMIC_RELAXED, __HIP_MEMORY_SCOPE_AGENT);
        __builtin_amdgcn_sched_barrier(0);

        // ===================== half B =====================
        {
            f32x4 acc[4][2] = {};
#pragma unroll
            for (int ks = 0; ks < 4; ++ks)
#pragma unroll
                for (int oi = 0; oi < 4; ++oi)
#pragma unroll
                    for (int bi = 0; bi < 2; ++bi)
                        acc[oi][bi] = MFMA16(Wf[oi][ks], afB[bi][ks], acc[oi][bi]);
#pragma unroll
            for (int oi = 0; oi < 4; ++oi)
#pragma unroll
                for (int bi = 0; bi < 2; ++bi)
                    *(f32x4*)&part[wsl[oi] + bi * 1024] = acc[oi][bi];
        }
        __syncthreads();   // sync3: partials B visible

        {
            float l[4];
#pragma unroll
            for (int g4 = 0; g4 < 4; ++g4) {
                float s = xwB[g4];
#pragma unroll
                for (int k8 = 0; k8 < 8; ++k8)
                    s += part[k8 * 2048 + rsl[g4]];
                l[g4] = s;
            }
            const float rg = fast_sigmoid(l[0] - fbv);
            const float fg = fast_sigmoid(l[1] + fbv);
            const float ug = fast_tanh(l[2]);
            const float og = fast_sigmoid(l[3]);
            const float of = 1.f - fg;
            const float gg = rg * (1.f - of * of) + (1.f - rg) * (fg * fg);
            cB = gg * cB + (1.f - gg) * ug;
            hB = og * fast_tanh(cB);
            const unsigned hw = (unsigned)f2bf(hB);
            asm volatile("global_store_short %0, %1, off sc1"
                         :: "v"(hn + (32 + bb) * 1024 + ch), "v"(hw) : "memory");
        }
        asm volatile("s_waitcnt vmcnt(0)" ::: "memory");   // h_B at L3
        __syncthreads();   // sync4
        if (tid == 0)
            __hip_atomic_fetch_add(sigB, 1u, __ATOMIC_RELAXED, __HIP_MEMORY_SCOPE_AGENT);
        __builtin_amdgcn_sched_barrier(0);

        // ---- tail: out stores + xW(t+1) prefetch (drain covered by next A phase) ----
        *orA = hA; orA += 1024;
        *orB = hB; orB += 1024;
        {
            const int tp = (t < 511) ? t + 1 : 511;
            const size_t tb = (size_t)tp * 262144;
#pragma unroll
            for (int g4 = 0; g4 < 4; ++g4) {
                if constexpr (XWF32) {
                    xwA[g4] = xw32[tb + xbA + g4 * 1024];
                    xwB[g4] = xw32[tb + xbB + g4 * 1024];
                } else {
                    xwA[g4] = bf2f(xw16[tb + xbA + g4 * 1024]);
                    xwB[g4] = bf2f(xw16[tb + xbB + g4 * 1024]);
                }
            }
        }
        __builtin_amdgcn_sched_barrier(0);
    }

    hcout[bb * 1024 + ch] = hA;
    hcout[65536 + bb * 1024 + ch] = cA;
    hcout[(32 + bb) * 1024 + ch] = hB;
    hcout[65536 + (32 + bb) * 1024 + ch] = cB;
}

extern "C" void kernel_launch(void* const* d_in, const int* in_sizes, int n_in,
                              void* d_out, int out_size, void* d_ws, size_t ws_size,
                              hipStream_t stream) {
    const float* x   = (const float*)d_in[0];
    const float* wih = (const float*)d_in[1];
    const float* bih = (const float*)d_in[2];
    const float* whh = (const float*)d_in[3];
    const float* bhh = (const float*)d_in[4];
    const float* fb  = (const float*)d_in[5];
    const float* h0  = (const float*)d_in[6];
    const float* c0  = (const float*)d_in[7];

    char* ws = (char*)d_ws;
    float* out = (float*)d_out;
    float* hc  = out + 33554432;  // h_n, then c_n

    unsigned short* xb   = (unsigned short*)(ws + OFF_XB);
    unsigned short* wihb = (unsigned short*)(ws + OFF_WIH);
    unsigned short* whhb = (unsigned short*)(ws + OFF_WHH);
    float* bias          = (float*)(ws + OFF_BIAS);
    unsigned short* hb0  = (unsigned short*)(ws + OFF_H0);
    unsigned short* hb1  = (unsigned short*)(ws + OFF_H1);
    unsigned int* flags  = (unsigned int*)(ws + OFF_FLG);
    void* xw             = (void*)(ws + OFF_XW);

    const bool f32path = ws_size >= OFF_XW + XW_F32_BYTES;

    cast4_kernel<<<32768, 256, 0, stream>>>(x, xb, 8388608);
    cast4_kernel<<<4096, 256, 0, stream>>>(wih, wihb, 1048576);
    cast4_kernel<<<4096, 256, 0, stream>>>(whh, whhb, 1048576);
    init_misc<<<256, 256, 0, stream>>>(bih, bhh, bias, h0, hb0, flags);

    dim3 g(256, 32);
    if (f32path) xw_gemm<true><<<g, 256, 0, stream>>>(xb, wihb, bias, xw);
    else         xw_gemm<false><<<g, 256, 0, stream>>>(xb, wihb, bias, xw);

    const float* fbp = fb;
    const float* c0p = c0;
    void* xwp = xw;
    const unsigned short* whhp = whhb;
    unsigned int* ctr = flags;
    void* kargs[] = { &hb0, &hb1, &xwp, &whhp, &fbp, &c0p, &out, &hc, &ctr };
    if (f32path)
        hipLaunchCooperativeKernel((void*)lstm_persistent<true>, dim3(64), dim3(512),
                                   kargs, 0, stream);
    else
        hipLaunchCooperativeKernel((void*)lstm_persistent<false>, dim3(64), dim3(512),
                                   kargs, 0, stream);
}

// Round 12
// 3688.003 us; speedup vs baseline: 1.2543x; 1.2543x over previous
//
#include <hip/hip_runtime.h>
#include <stdint.h>
#include <stddef.h>

typedef __attribute__((ext_vector_type(8))) short short8;
typedef __attribute__((ext_vector_type(4))) float f32x4;
typedef __attribute__((ext_vector_type(2))) float f32x2;

#define MFMA16(A, B, C) __builtin_amdgcn_mfma_f32_16x16x32_bf16((A), (B), (C), 0, 0, 0)

// ---------- workspace layout (bytes) ----------
static const size_t OFF_WIH  = 67108864;             // w_ih bf16   [4096, 1024]     8388608
static const size_t OFF_WHH  = 75497472;             // w_hh bf16   [4096, 1024]     8388608
static const size_t OFF_BIAS = 83886080;             // b_ih+b_hh   [4096] f32         16384
static const size_t OFF_H0   = 83902464;             // h buf 0 bf16 [64,1024]        131072
static const size_t OFF_H1   = 84033536;             // h buf 1 bf16                  131072
static const size_t OFF_FLG  = 84164608;             // u32[512]: sync ctr[0..255], xwprog[256..511]
static const size_t OFF_XW   = 84426752;             // xW [512*64, 4096] f32 or bf16
static const size_t XW_F32_BYTES = 536870912;

__device__ __forceinline__ unsigned short f2bf(float f) {
    union { float f; uint32_t u; } v; v.f = f;
    uint32_t u = v.u;
    u += 0x7FFFu + ((u >> 16) & 1u);   // round-to-nearest-even
    return (unsigned short)(u >> 16);
}
__device__ __forceinline__ float bf2f(unsigned short b) {
    union { uint32_t u; float f; } v; v.u = ((uint32_t)b) << 16;
    return v.f;
}

__device__ __forceinline__ float fast_sigmoid(float x) {
    return 1.f / (1.f + __expf(-x));
}
__device__ __forceinline__ float fast_tanh(float x) {
    return 1.f - 2.f / (__expf(2.f * x) + 1.f);
}

// ---------- cast fp32 -> bf16, 4 elems/thread (weights only now) ----------
__global__ __launch_bounds__(256) void cast4_kernel(const float* __restrict__ s,
                                                    unsigned short* __restrict__ d, int n4) {
    int i = blockIdx.x * 256 + threadIdx.x;
    if (i >= n4) return;
    float4 f = ((const float4*)s)[i];
    ushort4 o;
    o.x = f2bf(f.x); o.y = f2bf(f.y); o.z = f2bf(f.z); o.w = f2bf(f.w);
    ((ushort4*)d)[i] = o;
}

// ---------- bias fold + h0 init + counter zero ----------
__global__ __launch_bounds__(256) void init_misc(const float* __restrict__ b_ih,
                                                 const float* __restrict__ b_hh,
                                                 float* __restrict__ bias,
                                                 const float* __restrict__ h0,
                                                 unsigned short* __restrict__ h_ini,
                                                 unsigned int* __restrict__ flags) {
    int i = blockIdx.x * 256 + threadIdx.x;
    if (i < 512) flags[i] = 0u;
    if (i < 4096) bias[i] = b_ih[i] + b_hh[i];
    if (i < 65536) h_ini[i] = f2bf(h0[i]);
}

// ---------- FUSED cooperative kernel: 256 blocks x 512 thr ----------
// blocks 0..63   : round-10 persistent recurrence (byte-identical structure; xW loads
//                  are sc1 asm + per-bm readiness poll folded into the tail prefetch).
// blocks 64..255 : persistent xW-GEMM producers. Tiles 128x128, t-ordered round-robin
//                  (tau = g, g+192, ...). x cast f32->bf16 in-register during staging
//                  (x-cast kernel eliminated). Stores sc1 (write-through L3: no kernel
//                  boundary flush inside the fused launch); after vmcnt(0)+barrier,
//                  tid0 bumps xwprog[bm] (32 tiles per bm = 2 timesteps).
template <bool XWF32>
__global__ __launch_bounds__(512, 2) void fused_kernel(
        unsigned short* hb0, unsigned short* hb1,
        void* xw,
        const unsigned short* __restrict__ whh,
        const unsigned short* __restrict__ wih,
        const float* __restrict__ x,
        const float* __restrict__ bias,
        const float* __restrict__ fb,
        const float* __restrict__ c0,
        float* __restrict__ out,
        float* __restrict__ hcout,
        unsigned int* flags) {
    __shared__ __align__(16) char smem[131072];
    const int tid = threadIdx.x;
    const int wave = tid >> 6, lane = tid & 63;
    unsigned int* xwprog = flags + 256;

    if (blockIdx.x >= 64) {
        // ==================== GEMM producer ====================
        unsigned short* As = (unsigned short*)smem;           // 8 KB
        unsigned short* Bs = (unsigned short*)(smem + 8192);  // 8 KB
        const int g = blockIdx.x - 64;                        // 0..191
        const int wm = (wave & 3) * 32, wn = (wave >> 2) * 64;
        const int lr = lane & 15, lk = (lane >> 4) * 8;
        const int r0 = tid >> 2, k0c = (tid & 3) * 8;
        const int rbase = (lane >> 4) * 4;

        for (int tau = g; tau < 8192; tau += 192) {
            const int bm = tau >> 5, bn = tau & 31;
            const int m = bm * 128 + r0;                      // out row = t*64+b
            const float* pax = x + (size_t)((m & 63) * 512 + (m >> 6)) * 1024 + k0c;
            const unsigned short* pbw = wih + (size_t)(bn * 128 + r0) * 1024 + k0c;
            unsigned short* sa = As + r0 * 32 + k0c;
            unsigned short* sb = Bs + r0 * 32 + k0c;

            f32x4 acc[2][4] = {};
            for (int kk = 0; kk < 32; ++kk) {
                const int ko = kk * 32;
                float4 a0 = *(const float4*)(pax + ko);
                float4 a1 = *(const float4*)(pax + ko + 4);
                uint4 bv = *(const uint4*)(pbw + ko);
                __syncthreads();
                ushort4 ca, cb;
                ca.x = f2bf(a0.x); ca.y = f2bf(a0.y); ca.z = f2bf(a0.z); ca.w = f2bf(a0.w);
                cb.x = f2bf(a1.x); cb.y = f2bf(a1.y); cb.z = f2bf(a1.z); cb.w = f2bf(a1.w);
                *(ushort4*)sa = ca;
                *(ushort4*)(sa + 4) = cb;
                *(uint4*)sb = bv;
                __syncthreads();
                short8 af0 = *(const short8*)(As + (wm + lr) * 32 + lk);
                short8 af1 = *(const short8*)(As + (wm + 16 + lr) * 32 + lk);
                short8 bf4[4];
#pragma unroll
                for (int ni = 0; ni < 4; ++ni)
                    bf4[ni] = *(const short8*)(Bs + (wn + ni * 16 + lr) * 32 + lk);
#pragma unroll
                for (int ni = 0; ni < 4; ++ni) {
                    acc[0][ni] = MFMA16(af0, bf4[ni], acc[0][ni]);
                    acc[1][ni] = MFMA16(af1, bf4[ni], acc[1][ni]);
                }
            }
            // epilogue: bias + sc1 stores (write-through to L3)
#pragma unroll
            for (int ni = 0; ni < 4; ++ni) {
                const int gc = bn * 128 + wn + ni * 16 + lr;
                const float bvs = bias[gc];
#pragma unroll
                for (int mi = 0; mi < 2; ++mi) {
                    const int gr = bm * 128 + wm + mi * 16 + rbase;
#pragma unroll
                    for (int r = 0; r < 4; ++r) {
                        const float v = acc[mi][ni][r] + bvs;
                        if constexpr (XWF32) {
                            float* p = (float*)xw + (size_t)(gr + r) * 4096 + gc;
                            asm volatile("global_store_dword %0, %1, off sc1"
                                         :: "v"(p), "v"(v) : "memory");
                        } else {
                            unsigned short* p = (unsigned short*)xw + (size_t)(gr + r) * 4096 + gc;
                            const unsigned int hv = f2bf(v);
                            asm volatile("global_store_short %0, %1, off sc1"
                                         :: "v"(p), "v"(hv) : "memory");
                        }
                    }
                }
            }
            asm volatile("s_waitcnt vmcnt(0)" ::: "memory");   // stores at L3
            __syncthreads();
            if (tid == 0)
                __hip_atomic_fetch_add(&xwprog[bm], 1u, __ATOMIC_RELAXED,
                                       __HIP_MEMORY_SCOPE_AGENT);
        }
        return;
    }

    // ==================== recurrence consumer (round-10 structure) ====================
    float* part = (float*)smem;                       // [kq][batch][out] 131072 B
    const int bk = blockIdx.x, ch0 = bk * 16;
    const int kq = wave;                              // K-slice owner
    const int lr = lane & 15, g = lane >> 4;
    unsigned int* ctr = flags;

    // ---- W_hh fragments -> registers, once ----
    short8 Wf[4][4];
#pragma unroll
    for (int ni = 0; ni < 4; ++ni)
#pragma unroll
        for (int ks = 0; ks < 4; ++ks) {
            const unsigned short* p = whh + (size_t)(ni * 1024 + ch0 + lr) * 1024
                                          + kq * 128 + ks * 32 + g * 8;
            asm volatile("global_load_dwordx4 %0, %1, off"
                         : "=&v"(Wf[ni][ks]) : "v"(p));
        }
    asm volatile("s_waitcnt vmcnt(0)" ::: "memory");
    __builtin_amdgcn_sched_barrier(0);

    // ---- per-thread epilogue map ----
    const int b  = tid >> 3;
    const int j0 = 2 * (tid & 7);
    const int ch = ch0 + j0;
    const float fb0 = fb[ch], fb1 = fb[ch + 1];
    float c0r = c0[b * 1024 + ch], c1r = c0[b * 1024 + ch + 1];

    // ---- loop-invariant LDS indices (round-8 verified swizzle) ----
    int wsl[4];
#pragma unroll
    for (int oi = 0; oi < 4; ++oi)
        wsl[oi] = kq * 4096 + lr * 64 + (((oi * 4 + g) ^ (lr & 7)) * 4);
    int rsl[4];
#pragma unroll
    for (int g4 = 0; g4 < 4; ++g4)
        rsl[g4] = b * 64 + (((g4 * 4 + (j0 >> 2)) ^ (b & 7)) * 4) + (j0 & 3);

    // ---- pointers / sync addresses ----
    const float* xwf = (const float*)xw + (size_t)b * 4096 + ch;
    const unsigned short* xwb = (const unsigned short*)xw + (size_t)b * 4096 + ch;
    float* orun = out + (size_t)b * 524288 + ch;
    unsigned int* my_sig  = &ctr[(bk >> 3) * 32];
    unsigned int* my_poll = &ctr[kq * 32];

    // ---- wait for xW(t=0) (bm 0 complete), then sc1 prefetch ----
    {
        const unsigned int* pr0 = &xwprog[0];
        while (__hip_atomic_load(pr0, __ATOMIC_RELAXED, __HIP_MEMORY_SCOPE_AGENT) < 32u) {}
    }
    __builtin_amdgcn_sched_barrier(0);
    f32x2 xf[4];
    uint32_t xu[4];
    if constexpr (XWF32) {
        asm volatile(
            "global_load_dwordx2 %0, %4, off sc1\n\t"
            "global_load_dwordx2 %1, %5, off sc1\n\t"
            "global_load_dwordx2 %2, %6, off sc1\n\t"
            "global_load_dwordx2 %3, %7, off sc1"
            : "=&v"(xf[0]), "=&v"(xf[1]), "=&v"(xf[2]), "=&v"(xf[3])
            : "v"(xwf), "v"(xwf + 1024), "v"(xwf + 2048), "v"(xwf + 3072));
    } else {
        asm volatile(
            "global_load_dword %0, %4, off sc1\n\t"
            "global_load_dword %1, %5, off sc1\n\t"
            "global_load_dword %2, %6, off sc1\n\t"
            "global_load_dword %3, %7, off sc1"
            : "=&v"(xu[0]), "=&v"(xu[1]), "=&v"(xu[2]), "=&v"(xu[3])
            : "v"(xwb), "v"(xwb + 1024), "v"(xwb + 2048), "v"(xwb + 3072));
    }
    asm volatile("s_waitcnt vmcnt(0)" ::: "memory");
    __builtin_amdgcn_sched_barrier(0);

    float h0v = 0.f, h1v = 0.f;

    for (int t = 0; t < 512; ++t) {
        const unsigned short* hp = (t & 1) ? hb1 : hb0;
        unsigned short* hn       = (t & 1) ? hb0 : hb1;

        // ---- per-wave poll: only MY K-slice's 8 producers ----
        if (t > 0) {
            const unsigned tgt = (unsigned)t * 8u;
            while (__hip_atomic_load(my_poll, __ATOMIC_RELAXED,
                                     __HIP_MEMORY_SCOPE_AGENT) < tgt) {}
        }
        __builtin_amdgcn_sched_barrier(0);

        // ---- 16 PARALLEL h sc1 loads ----
        short8 af[4][4];
        {
            const unsigned short* hbase = hp + (size_t)lr * 1024 + kq * 128 + g * 8;
#pragma unroll
            for (int bi = 0; bi < 4; ++bi) {
                const unsigned short* p = hbase + (size_t)bi * 16 * 1024;
                asm volatile(
                    "global_load_dwordx4 %0, %4, off sc1\n\t"
                    "global_load_dwordx4 %1, %4, off offset:64 sc1\n\t"
                    "global_load_dwordx4 %2, %4, off offset:128 sc1\n\t"
                    "global_load_dwordx4 %3, %4, off offset:192 sc1"
                    : "=&v"(af[bi][0]), "=&v"(af[bi][1]),
                      "=&v"(af[bi][2]), "=&v"(af[bi][3])
                    : "v"(p));
            }
        }
        asm volatile("s_waitcnt vmcnt(0)" ::: "memory");
        __builtin_amdgcn_sched_barrier(0);

        // ---- 64 MFMA, transposed: D rows = outputs, cols = batch ----
        f32x4 acc[4][4] = {};
#pragma unroll
        for (int ks = 0; ks < 4; ++ks)
#pragma unroll
            for (int oi = 0; oi < 4; ++oi)
#pragma unroll
                for (int bi = 0; bi < 4; ++bi)
                    acc[oi][bi] = MFMA16(Wf[oi][ks], af[bi][ks], acc[oi][bi]);

        // ---- partials: 16 x ds_write_b128, swizzled ----
#pragma unroll
        for (int oi = 0; oi < 4; ++oi)
#pragma unroll
            for (int bi = 0; bi < 4; ++bi)
                *(f32x4*)&part[wsl[oi] + bi * 1024] = acc[oi][bi];
        __syncthreads();

        // ---- 8-way K-reduce + gates + state update ----
        float l0[4], l1[4];
#pragma unroll
        for (int g4 = 0; g4 < 4; ++g4) {
            float s0, s1;
            if constexpr (XWF32) { s0 = xf[g4].x; s1 = xf[g4].y; }
            else { s0 = bf2f((unsigned short)xu[g4]);
                   s1 = bf2f((unsigned short)(xu[g4] >> 16)); }
#pragma unroll
            for (int k8 = 0; k8 < 8; ++k8) {
                const float2 v = *(const float2*)&part[k8 * 4096 + rsl[g4]];
                s0 += v.x; s1 += v.y;
            }
            l0[g4] = s0; l1[g4] = s1;
        }
        const float rg0 = fast_sigmoid(l0[0] - fb0);
        const float fg0 = fast_sigmoid(l0[1] + fb0);
        const float ug0 = fast_tanh(l0[2]);
        const float og0 = fast_sigmoid(l0[3]);
        const float rg1 = fast_sigmoid(l1[0] - fb1);
        const float fg1 = fast_sigmoid(l1[1] + fb1);
        const float ug1 = fast_tanh(l1[2]);
        const float og1 = fast_sigmoid(l1[3]);
        const float of0 = 1.f - fg0, of1 = 1.f - fg1;
        const float gg0 = rg0 * (1.f - of0 * of0) + (1.f - rg0) * (fg0 * fg0);
        const float gg1 = rg1 * (1.f - of1 * of1) + (1.f - rg1) * (fg1 * fg1);
        c0r = gg0 * c0r + (1.f - gg0) * ug0;
        c1r = gg1 * c1r + (1.f - gg1) * ug1;
        h0v = og0 * fast_tanh(c0r);
        h1v = og1 * fast_tanh(c1r);

        // h (cross-block): one u32 agent-scope store -> straight to L3
        const unsigned hw = ((unsigned)f2bf(h1v) << 16) | (unsigned)f2bf(h0v);
        __hip_atomic_store((unsigned int*)&hn[b * 1024 + ch], hw,
                           __ATOMIC_RELAXED, __HIP_MEMORY_SCOPE_AGENT);

        // ---- drain h stores block-wide, then signal my group's counter ----
        __syncthreads();
        if (tid == 0)
            __hip_atomic_fetch_add(my_sig, 1u, __ATOMIC_RELAXED,
                                   __HIP_MEMORY_SCOPE_AGENT);
        __builtin_amdgcn_sched_barrier(0);

        // ---- post-signal tail: out store + xW(t+1) readiness + sc1 prefetch ----
        *(f32x2*)orun = (f32x2){h0v, h1v};
        orun += 1024;
        {
            const int tp = (t < 511) ? t + 1 : 511;
            if (!(tp & 1)) {   // new bm slab: ensure producers finished it
                const unsigned int* pr = &xwprog[tp >> 1];
                while (__hip_atomic_load(pr, __ATOMIC_RELAXED,
                                         __HIP_MEMORY_SCOPE_AGENT) < 32u) {}
            }
            if constexpr (XWF32) {
                const float* p0 = xwf + (size_t)tp * 262144;
                asm volatile(
                    "global_load_dwordx2 %0, %4, off sc1\n\t"
                    "global_load_dwordx2 %1, %5, off sc1\n\t"
                    "global_load_dwordx2 %2, %6, off sc1\n\t"
                    "global_load_dwordx2 %3, %7, off sc1"
                    : "=&v"(xf[0]), "=&v"(xf[1]), "=&v"(xf[2]), "=&v"(xf[3])
                    : "v"(p0), "v"(p0 + 1024), "v"(p0 + 2048), "v"(p0 + 3072));
            } else {
                const unsigned short* p0 = xwb + (size_t)tp * 262144;
                asm volatile(
                    "global_load_dword %0, %4, off sc1\n\t"
                    "global_load_dword %1, %5, off sc1\n\t"
                    "global_load_dword %2, %6, off sc1\n\t"
                    "global_load_dword %3, %7, off sc1"
                    : "=&v"(xu[0]), "=&v"(xu[1]), "=&v"(xu[2]), "=&v"(xu[3])
                    : "v"(p0), "v"(p0 + 1024), "v"(p0 + 2048), "v"(p0 + 3072));
            }
        }
        asm volatile("s_waitcnt vmcnt(0)" ::: "memory");   // tail drain
        __builtin_amdgcn_sched_barrier(0);
    }

    *(f32x2*)&hcout[b * 1024 + ch] = (f32x2){h0v, h1v};
    *(f32x2*)&hcout[65536 + b * 1024 + ch] = (f32x2){c0r, c1r};
}

extern "C" void kernel_launch(void* const* d_in, const int* in_sizes, int n_in,
                              void* d_out, int out_size, void* d_ws, size_t ws_size,
                              hipStream_t stream) {
    const float* x   = (const float*)d_in[0];
    const float* wih = (const float*)d_in[1];
    const float* bih = (const float*)d_in[2];
    const float* whh = (const float*)d_in[3];
    const float* bhh = (const float*)d_in[4];
    const float* fb  = (const float*)d_in[5];
    const float* h0  = (const float*)d_in[6];
    const float* c0  = (const float*)d_in[7];

    char* ws = (char*)d_ws;
    float* out = (float*)d_out;
    float* hc  = out + 33554432;  // h_n, then c_n

    unsigned short* wihb = (unsigned short*)(ws + OFF_WIH);
    unsigned short* whhb = (unsigned short*)(ws + OFF_WHH);
    float* bias          = (float*)(ws + OFF_BIAS);
    unsigned short* hb0  = (unsigned short*)(ws + OFF_H0);
    unsigned short* hb1  = (unsigned short*)(ws + OFF_H1);
    unsigned int* flags  = (unsigned int*)(ws + OFF_FLG);
    void* xw             = (void*)(ws + OFF_XW);

    const bool f32path = ws_size >= OFF_XW + XW_F32_BYTES;

    cast4_kernel<<<4096, 256, 0, stream>>>(wih, wihb, 1048576);
    cast4_kernel<<<4096, 256, 0, stream>>>(whh, whhb, 1048576);
    init_misc<<<256, 256, 0, stream>>>(bih, bhh, bias, h0, hb0, flags);

    const float* xp = x;
    const float* fbp = fb;
    const float* c0p = c0;
    void* xwp = xw;
    const unsigned short* whhp = whhb;
    const unsigned short* wihp = wihb;
    const float* biasp = bias;
    void* kargs[] = { &hb0, &hb1, &xwp, &whhp, &wihp, &xp, &biasp, &fbp, &c0p,
                      &out, &hc, &flags };
    if (f32path)
        hipLaunchCooperativeKernel((void*)fused_kernel<true>, dim3(256), dim3(512),
                                   kargs, 0, stream);
    else
        hipLaunchCooperativeKernel((void*)fused_kernel<false>, dim3(256), dim3(512),
                                   kargs, 0, stream);
}